// Round 5
// baseline (366.099 us; speedup 1.0000x reference)
//
#include <hip/hip_runtime.h>
#include <hip/hip_bf16.h>

constexpr int N = 10000;   // nodes
constexpr int D = 512;     // feature dim
constexpr int E = 160000;  // edges
constexpr int L = 3;       // layers
constexpr float EPS = 1e-5f;

typedef _Float16 half8 __attribute__((ext_vector_type(8)));
typedef _Float16 half2v __attribute__((ext_vector_type(2)));
typedef float floatx4 __attribute__((ext_vector_type(4)));

// ---------------------------------------------------------------------------
// Mega setup: degrees + x fp32->f16 conversion + column stats + W transpose.
// Roles by blockIdx.x.
// ---------------------------------------------------------------------------
constexpr int DEG_BLOCKS  = (E + 255) / 256;   // 625
constexpr int CONV_BLOCKS = 100;               // 100 rows each
constexpr int TW_BLOCKS   = L * 256;           // 768 (32x32 tiles)
constexpr int MEGA_BLOCKS = DEG_BLOCKS + CONV_BLOCKS + TW_BLOCKS;

__global__ __launch_bounds__(256) void mega_setup(
    const int* __restrict__ src, const int* __restrict__ dst,
    const float* __restrict__ x, const float* __restrict__ W,
    int* __restrict__ out_deg, int* __restrict__ in_deg,
    _Float16* __restrict__ x16, float* __restrict__ stats0,
    _Float16* __restrict__ Wt) {
    __shared__ float tb[32][33];
    int bid = blockIdx.x;
    int tid = threadIdx.x;
    if (bid < DEG_BLOCKS) {
        int e = bid * 256 + tid;
        if (e < E) {
            atomicAdd(&out_deg[src[e]], 1);
            atomicAdd(&in_deg[dst[e]], 1);
        }
    } else if (bid < DEG_BLOCKS + CONV_BLOCKS) {
        int b = bid - DEG_BLOCKS;
        int r0 = b * 100;
        int r1 = r0 + 100; if (r1 > N) r1 = N;
        int c2 = tid * 2;
        float s0 = 0.f, s1 = 0.f, q0 = 0.f, q1 = 0.f;
        for (int r = r0; r < r1; ++r) {
            float2 v = *(const float2*)(x + (size_t)r * D + c2);
            s0 += v.x; q0 += v.x * v.x;
            s1 += v.y; q1 += v.y * v.y;
            half2v h; h[0] = (_Float16)v.x; h[1] = (_Float16)v.y;
            *(half2v*)(x16 + (size_t)r * D + c2) = h;
        }
        atomicAdd(&stats0[c2], s0);
        atomicAdd(&stats0[c2 + 1], s1);
        atomicAdd(&stats0[D + c2], q0);
        atomicAdd(&stats0[D + c2 + 1], q1);
    } else {
        int b = bid - DEG_BLOCKS - CONV_BLOCKS;  // 0..767
        int l = b >> 8;
        int t = b & 255;
        int k0 = (t >> 4) * 32, n0 = (t & 15) * 32;
        int tx = tid & 31, ty = tid >> 5;  // 32 x 8
        const float* Wl = W + (size_t)l * D * D;
        _Float16* Wtl = Wt + (size_t)l * D * D;
        for (int i = 0; i < 32; i += 8)
            tb[ty + i][tx] = Wl[(size_t)(k0 + ty + i) * D + n0 + tx];
        __syncthreads();
        for (int i = 0; i < 32; i += 8)
            Wtl[(size_t)(n0 + ty + i) * D + k0 + tx] = (_Float16)tb[tx][ty + i];
    }
}

// ---------------------------------------------------------------------------
// Single block: exclusive scan of in_deg -> off & cursor, plus both norms.
// ---------------------------------------------------------------------------
__global__ void scan_indeg(const int* __restrict__ in_deg,
                           const int* __restrict__ out_deg,
                           int* __restrict__ off, int* __restrict__ cursor,
                           float* __restrict__ src_norm, float* __restrict__ dst_norm) {
    __shared__ int lsum[1024];
    int t = threadIdx.x;
    const int chunk = (N + 1023) / 1024;
    int start = t * chunk;
    int end = start + chunk; if (end > N) end = N;
    int s = 0;
    for (int i = start; i < end; ++i) s += in_deg[i];
    lsum[t] = s;
    __syncthreads();
    for (int d = 1; d < 1024; d <<= 1) {
        int v = (t >= d) ? lsum[t - d] : 0;
        __syncthreads();
        lsum[t] += v;
        __syncthreads();
    }
    int excl = (t == 0) ? 0 : lsum[t - 1];
    for (int i = start; i < end; ++i) {
        off[i] = excl;
        cursor[i] = excl;
        excl += in_deg[i];
        int od = out_deg[i]; if (od < 1) od = 1;
        int id = in_deg[i];  if (id < 1) id = 1;
        src_norm[i] = rsqrtf((float)od);
        dst_norm[i] = rsqrtf((float)id);
    }
    if (t == 1023) off[N] = lsum[1023];
}

__global__ void csr_fill(const int* __restrict__ src, const int* __restrict__ dst,
                         int* __restrict__ cursor, int* __restrict__ csr_src) {
    int e = blockIdx.x * blockDim.x + threadIdx.x;
    if (e >= E) return;
    int d = dst[e];
    int pos = atomicAdd(&cursor[d], 1);
    csr_src[pos] = src[e];
}

// ---------------------------------------------------------------------------
// Fused layer: BN(coefs in-register) + gather-aggregate into LDS + MFMA matmul
// + bias + relu + (optional) next-layer column stats.
// One block (256 thr, 4 waves) per 16-row strip; 625 blocks exactly.
// Stage 1: wave w aggregates rows w*4..w*4+3 into LDS As (f16, padded).
// Stage 2: wave w computes output cols [w*128,(w+1)*128) for all 16 rows:
//   8 accumulators of mfma_f32_16x16x32_f16; A-frag from LDS, B from L2-hot Wt.
// ---------------------------------------------------------------------------
constexpr int RP = 520;  // padded LDS row stride (f16 elems): +16B breaks bank aliasing

template <typename OutT, bool STATS>
__global__ __launch_bounds__(256) void fused_layer(
    const _Float16* __restrict__ xin, const int* __restrict__ off,
    const int* __restrict__ csr_src, const float* __restrict__ src_norm,
    const float* __restrict__ dst_norm, const float* __restrict__ stats_in,
    const float* __restrict__ gamma, const float* __restrict__ beta,
    const _Float16* __restrict__ Bt, const float* __restrict__ bias,
    OutT* __restrict__ Cout, float* __restrict__ stats_out) {
    __shared__ __align__(16) _Float16 As[16 * RP];
    const int tid  = threadIdx.x;
    const int wave = tid >> 6;
    const int lane = tid & 63;
    const int quad = lane >> 4;
    const int l16  = lane & 15;
    const int row_base = blockIdx.x * 16;
    const int c0 = lane * 8;

    // BN coefs for this lane's 8 columns (per-wave redundant, trivial cost)
    float scale[8], shift[8];
    const float invN = 1.0f / (float)N;
    for (int i = 0; i < 8; ++i) {
        int c = c0 + i;
        float mu = stats_in[c] * invN;
        float var = stats_in[D + c] * invN - mu * mu;
        float sc = gamma[c] * rsqrtf(var + EPS);
        scale[i] = sc;
        shift[i] = beta[c] - mu * sc;
    }

    // ---- Stage 1: aggregate 4 rows per wave into LDS ----
    for (int i = 0; i < 4; ++i) {
        int r = wave * 4 + i;
        int n = row_base + r;
        int e0 = off[n], e1 = off[n + 1];
        float a[8] = {}, a2[8] = {};
        float t = 0.f;
        int e = e0;
        for (; e + 2 <= e1; e += 2) {
            int s0 = csr_src[e];
            int s1 = csr_src[e + 1];
            float n0 = src_norm[s0];
            float n1 = src_norm[s1];
            half8 v0 = *(const half8*)(xin + (size_t)s0 * D + c0);
            half8 v1 = *(const half8*)(xin + (size_t)s1 * D + c0);
            t += n0 + n1;
            for (int k = 0; k < 8; ++k) {
                a[k]  += (float)v0[k] * n0;
                a2[k] += (float)v1[k] * n1;
            }
        }
        if (e < e1) {
            int s0 = csr_src[e];
            float n0 = src_norm[s0];
            half8 v0 = *(const half8*)(xin + (size_t)s0 * D + c0);
            t += n0;
            for (int k = 0; k < 8; ++k) a[k] += (float)v0[k] * n0;
        }
        float dn = dst_norm[n];
        half8 o;
        for (int k = 0; k < 8; ++k)
            o[k] = (_Float16)(dn * (scale[k] * (a[k] + a2[k]) + shift[k] * t));
        *(half8*)(As + r * RP + c0) = o;
    }
    __syncthreads();

    // ---- Stage 2: 16x512 @ 512x128 (this wave's col slice) ----
    const int colw = wave * 128;
    floatx4 acc[8] = {};
    #pragma unroll
    for (int k0 = 0; k0 < D; k0 += 32) {
        half8 af = *(const half8*)(As + l16 * RP + k0 + quad * 8);
        #pragma unroll
        for (int j = 0; j < 8; ++j) {
            half8 bf = *(const half8*)(Bt + (size_t)(colw + j * 16 + l16) * D + k0 + quad * 8);
            acc[j] = __builtin_amdgcn_mfma_f32_16x16x32_f16(af, bf, acc[j], 0, 0, 0);
        }
    }

    // ---- Epilogue: bias + relu + store + stats ----
    float s[8] = {}, q[8] = {};
    for (int j = 0; j < 8; ++j) {
        int col = colw + j * 16 + l16;
        float bi = bias[col];
        for (int r = 0; r < 4; ++r) {
            int row = row_base + quad * 4 + r;
            float v = acc[j][r] + bi;
            v = v > 0.f ? v : 0.f;
            Cout[(size_t)row * D + col] = (OutT)v;
            if (STATS) { s[j] += v; q[j] += v * v; }
        }
    }
    if (STATS) {
        for (int j = 0; j < 8; ++j) {
            float sv = s[j], qv = q[j];
            sv += __shfl_xor(sv, 16); sv += __shfl_xor(sv, 32);
            qv += __shfl_xor(qv, 16); qv += __shfl_xor(qv, 32);
            if (quad == 0) {
                int col = colw + j * 16 + l16;
                atomicAdd(&stats_out[col], sv);
                atomicAdd(&stats_out[D + col], qv);
            }
        }
    }
}

// ---------------------------------------------------------------------------
extern "C" void kernel_launch(void* const* d_in, const int* in_sizes, int n_in,
                              void* d_out, int out_size, void* d_ws, size_t ws_size,
                              hipStream_t stream) {
    const float* x_in  = (const float*)d_in[0];
    const int*   src   = (const int*)d_in[1];
    const int*   dst   = (const int*)d_in[2];
    const float* gamma = (const float*)d_in[3];
    const float* beta  = (const float*)d_in[4];
    const float* W     = (const float*)d_in[5];
    const float* b     = (const float*)d_in[6];
    float* out = (float*)d_out;

    // workspace carve-up (16B-aligned segments first)
    char* p = (char*)d_ws;
    _Float16* x16a = (_Float16*)p; p += (size_t)N * D * 2;       // 10.24 MB
    _Float16* x16b = (_Float16*)p; p += (size_t)N * D * 2;       // 10.24 MB
    _Float16* Wt   = (_Float16*)p; p += (size_t)L * D * D * 2;   // 1.57 MB
    float* src_norm = (float*)p;   p += (size_t)N * 4;
    float* dst_norm = (float*)p;   p += (size_t)N * 4;
    // contiguous zero-init region: out_deg, in_deg, stats0..2
    int* out_deg   = (int*)p;      p += (size_t)N * 4;
    int* in_deg    = (int*)p;      p += (size_t)N * 4;
    float* stats0  = (float*)p;    p += 2 * D * 4;
    float* stats1  = (float*)p;    p += 2 * D * 4;
    float* stats2  = (float*)p;    p += 2 * D * 4;
    int* csr_off   = (int*)p;      p += (size_t)(N + 1) * 4;
    int* cursor    = (int*)p;      p += (size_t)N * 4;
    int* csr_src   = (int*)p;      p += (size_t)E * 4;

    // --- setup ---
    hipMemsetAsync(out_deg, 0, (2 * (size_t)N + 6 * D) * sizeof(int), stream);
    mega_setup<<<MEGA_BLOCKS, 256, 0, stream>>>(src, dst, x_in, W,
                                                out_deg, in_deg, x16a, stats0, Wt);
    scan_indeg<<<1, 1024, 0, stream>>>(in_deg, out_deg, csr_off, cursor,
                                       src_norm, dst_norm);
    csr_fill<<<DEG_BLOCKS, 256, 0, stream>>>(src, dst, cursor, csr_src);

    const int blocks = N / 16;  // 625, exact

    // layer 0: read x16a -> write x16b
    fused_layer<_Float16, true><<<blocks, 256, 0, stream>>>(
        x16a, csr_off, csr_src, src_norm, dst_norm, stats0,
        gamma, beta, Wt, b, x16b, stats1);
    // layer 1: read x16b -> write x16a
    fused_layer<_Float16, true><<<blocks, 256, 0, stream>>>(
        x16b, csr_off, csr_src, src_norm, dst_norm, stats1,
        gamma + D, beta + D, Wt + (size_t)D * D, b + D, x16a, stats2);
    // layer 2: read x16a -> write out (fp32)
    fused_layer<float, false><<<blocks, 256, 0, stream>>>(
        x16a, csr_off, csr_src, src_norm, dst_norm, stats2,
        gamma + 2 * D, beta + 2 * D, Wt + 2 * (size_t)D * D, b + 2 * D, out, nullptr);
}